// Round 14
// baseline (136.257 us; speedup 1.0000x reference)
//
#include <hip/hip_runtime.h>
#include <math.h>
#include <stdint.h>

#define NM 8          // nmul
#define NPAR 12
#define GPB 16        // g's per block (64 lanes = 16 g x 4 pairs)
#define TCH 128       // timesteps per LDS chunk
#define ROWDW (GPB*3)           // dwords per step-row in LDS (48 = 192B)
#define CHDW (TCH*ROWDW)        // dwords per chunk buffer (6144 = 24KB)
#define NLL  (CHDW*4/1024)      // 1KB global_load_lds ops per chunk (24)

typedef __attribute__((address_space(1))) const void gv_t;
typedef __attribute__((address_space(3))) void lv_t;
typedef float v2f __attribute__((ext_vector_type(2)));
typedef _Float16 h2 __attribute__((ext_vector_type(2)));   // -> v_pk_*_f16

static __device__ __forceinline__ h2 h2min(h2 a, h2 b) { return __builtin_elementwise_min(a, b); }
static __device__ __forceinline__ h2 h2max(h2 a, h2 b) { return __builtin_elementwise_max(a, b); }
static __device__ __forceinline__ h2 mkh2(float a, float b) {
    h2 r; r.x = (_Float16)a; r.y = (_Float16)b; return r;
}

__global__ __launch_bounds__(64, 1) void hbv_kernel(
    const float* __restrict__ x,      // [T, G, 3]  (prcp, tmean, pet)
    const float* __restrict__ praw,   // [1, G, 12, NM] in [0,1)
    float* __restrict__ out,          // [T, G, NM]
    int G, int T)
{
    __shared__ float lds[2][CHDW];    // 49,152 B double-buffered forcing stage

    const int lane = threadIdx.x;
    const int b    = blockIdx.x;
    const int gl   = lane >> 2;       // g within block, 0..15
    const int pi   = lane & 3;        // pair index: chains m0=2*pi, m0+1
    const int g    = (b << 4) + gl;   // G % 16 == 0 (4000 -> 250 blocks)
    const int m0   = pi << 1;

    // Parameter bounds: BETA, FC, K0, K1, K2, LP, PERC, UZL, TT, CFMAX, CFR, CWH
    const float lb[NPAR] = {1.0f, 50.0f, 0.05f, 0.01f, 0.001f, 0.2f, 0.0f, 0.0f, -2.5f, 0.5f, 0.0f, 0.0f};
    const float ub[NPAR] = {6.0f, 1000.0f, 0.9f, 0.5f, 0.2f, 1.0f, 10.0f, 100.0f, 2.5f, 10.0f, 0.1f, 0.2f};

    float pA[NPAR], pB[NPAR];
    const float* pr = praw + (size_t)g * (NPAR * NM) + m0;
    #pragma unroll
    for (int i = 0; i < NPAR; ++i) {
        const float s = ub[i] - lb[i];
        pA[i] = pr[i * NM]     * s + lb[i];   // adjacent dwords -> dwordx2
        pB[i] = pr[i * NM + 1] * s + lb[i];
    }

    // ---- fp32 per-chain invariants ----
    const float TTa = pA[8],  TTb = pB[8];
    const float CFa = pA[9],  CFb = pB[9];
    const float nCMTTa = -(CFa * TTa),         nCMTTb = -(CFb * TTb);
    const float nCRa   = -(pA[10] * CFa),      nCRb   = -(pB[10] * CFb);
    const float CRTTa  = (pA[10] * CFa) * TTa, CRTTb  = (pB[10] * CFb) * TTb;
    const float CWa = pA[11], CWb = pB[11];
    const float FCa = pA[1],  FCb = pB[1];
    const float iLPa = 1.0f / (pA[5] * FCa),   iLPb = 1.0f / (pB[5] * FCb);
    const float BEa = pA[0], BEb = pB[0];
    const float nBLa = -BEa * __builtin_amdgcn_logf(FCa);   // -BETA*log2(FC)
    const float nBLb = -BEb * __builtin_amdgcn_logf(FCb);
    const float K2a = pA[4], K2b = pB[4];
    const float OK2a = 1.0f - K2a, OK2b = 1.0f - K2b;

    // ---- packed fp16 invariants (soil-deficit core + response) ----
    const h2 FC2  = mkh2(FCa, FCb);
    const h2 PC2  = mkh2(pA[6], pB[6]);
    const h2 UZL2 = mkh2(pA[7], pB[7]);
    const h2 K0h  = mkh2(pA[2], pB[2]);
    const h2 K1h  = mkh2(pA[3], pB[3]);
    const h2 Z2   = mkh2(0.0f, 0.0f);

    // fp32 states: snow (drift-sensitive) and slow reservoir
    float SPa = 0.001f, SPb = 0.001f, MWa = 0.001f, MWb = 0.001f;
    float SLZa = 0.001f, SLZb = 0.001f;
    // fp16 states: soil DEFICIT D = FC - SM (relative precision where it matters), SUZ
    h2 D   = mkh2(FCa - 0.001f, FCb - 0.001f);
    h2 SUZ = mkh2(0.001f, 0.001f);

    // ---- chunk-copy geometry (16B-aligned: row = 192B, G*12 = 48000) ----
    const char* xb = (const char*)x;
    const uint32_t xstep  = (uint32_t)G * 12u;
    const uint32_t gbase  = (uint32_t)(b << 4) * 12u;
    const uint32_t lin    = (uint32_t)lane * 16u;
    const uint32_t r0     = lin / 192u;
    const uint32_t c0     = lin % 192u;
    const uint32_t rowmax = (uint32_t)(T - 1);

    // 24 async 1KB copies HBM -> LDS; +1024B = 5 rows + 64B in the 192B raster
    #define ISSUE_CHUNK(cs_, nb_)                                              \
    {                                                                          \
        uint32_t row_ = (uint32_t)(cs_) + r0;                                  \
        uint32_t col_ = c0;                                                    \
        _Pragma("unroll")                                                      \
        for (int i_ = 0; i_ < NLL; ++i_) {                                     \
            const uint32_t rg_ = row_ < rowmax ? row_ : rowmax;                \
            const uint32_t go_ = rg_ * xstep + gbase + col_;                   \
            __builtin_amdgcn_global_load_lds((gv_t*)(xb + go_),                \
                (lv_t*)&lds[nb_][i_ * 256], 16, 0, 0);                         \
            row_ += 5u + (col_ >= 128u ? 1u : 0u);                             \
            col_  = (col_ >= 128u) ? (col_ - 128u) : (col_ + 64u);             \
        }                                                                      \
    }

    auto step = [&](float P, float Tt, float E) -> v2f {
        // --- fp32 classification + caps (exact thresholds) ---
        const float rainA = (Tt >= TTa) ? P : 0.0f;
        const float rainB = (Tt >= TTb) ? P : 0.0f;
        const float snowA = P - rainA,  snowB = P - rainB;
        const float mcA = fmaxf(fmaf(CFa, Tt, nCMTTa), 0.0f);
        const float mcB = fmaxf(fmaf(CFb, Tt, nCMTTb), 0.0f);
        const float rcA = fmaxf(fmaf(nCRa, Tt, CRTTa), 0.0f);
        const float rcB = fmaxf(fmaf(nCRb, Tt, CRTTb), 0.0f);

        // --- snow routine fp32 (SP drift + MW-cw cancellation need fp32) ---
        SPa += snowA;                             SPb += snowB;
        const float meltA = fminf(mcA, SPa);      const float meltB = fminf(mcB, SPb);
        MWa += meltA;                             MWb += meltB;
        SPa -= meltA;                             SPb -= meltB;
        const float refA = fminf(rcA, MWa);       const float refB = fminf(rcB, MWb);
        SPa += refA;                              SPb += refB;
        MWa -= refA;                              MWb -= refB;
        const float cwA = CWa * SPa;              const float cwB = CWb * SPb;
        const float tsA = fmaxf(MWa - cwA, 0.0f); const float tsB = fmaxf(MWb - cwB, 0.0f);
        MWa = fminf(MWa, cwA);                    MWb = fminf(MWb, cwB);

        // --- soil wetness fp32 (SM reconstructed from deficit; clamp vs D>FC by 1/2 ulp) ---
        const float smA = fmaxf(FCa - (float)D.x, 0.0f);
        const float smB = fmaxf(FCb - (float)D.y, 0.0f);
        const float swA = __builtin_amdgcn_exp2f(
            fminf(fmaf(BEa, __builtin_amdgcn_logf(smA), nBLa), 0.0f));  // log2(0)=-inf -> sw=0
        const float swB = __builtin_amdgcn_exp2f(
            fminf(fmaf(BEb, __builtin_amdgcn_logf(smB), nBLb), 0.0f));
        const float rtA = rainA + tsA;            const float rtB = rainB + tsB;
        const float rgA = rtA * swA;              const float rgB = rtB * swB;

        // --- packed D-form soil: all updates are small increments ---
        const h2 tmr = mkh2(rtA - rgA, rtB - rgB);     // rt - rg >= 0
        const h2 Pe2 = mkh2(E * iLPa, E * iLPb);
        const h2 Eh  = mkh2(E, E);
        const h2 D1  = D - tmr;                        // == FC - SM1
        const h2 ex  = h2max(Z2 - D1, Z2);             // == max(SM1-FC,0), rel-accurate at D~0
        const h2 D2  = h2max(D1, Z2);                  // == FC - min(SM1, FC)
        const h2 SM2 = FC2 - D2;
        const h2 et  = h2min(h2min(SM2, SM2 * Pe2), Eh);
        D = h2min(D2 + et, FC2);                       // SM = max(SM2-et, ~0); D <= FC

        // --- response packed (SUZ small-scale; relative fp16 fine) ---
        const h2 rg2 = mkh2(rgA, rgB);
        SUZ = SUZ + (rg2 + ex);
        const h2 pc = h2min(SUZ, PC2);
        SUZ = SUZ - pc;
        const h2 q0 = K0h * h2max(SUZ - UZL2, Z2);
        SUZ = SUZ - q0;
        const h2 q1 = K1h * SUZ;
        SUZ = SUZ - q1;
        const h2 q01 = q0 + q1;

        // --- SLZ reservoir + output sum fp32 ---
        const float slA = SLZa + (float)pc.x;
        const float slB = SLZb + (float)pc.y;
        const float q2A = K2a * slA;
        const float q2B = K2b * slB;
        SLZa = slA * OK2a;                             // == slA - q2A
        SLZb = slB * OK2b;
        v2f q; q.x = (float)q01.x + q2A; q.y = (float)q01.y + q2B;
        return q;
    };

    // --- pipeline: buf[c&1] computed while buf[(c+1)&1] streams in ---
    ISSUE_CHUNK(0, 0)

    char* ob = (char*)out;
    uint32_t ooff = (uint32_t)(g * NM + m0) * 4u;      // 8B-aligned (m0 even)
    const uint32_t ostep = (uint32_t)(G * NM) * 4u;

    int c = 0;
    for (int cs = 0; cs < T; cs += TCH, ++c) {
        const int nb = c & 1;
        if (cs + TCH < T) {
            ISSUE_CHUNK(cs + TCH, nb ^ 1)
            // newest NLL outstanding = next chunk's copies; <=NLL left means
            // THIS chunk's copies (and all older stores) retired.
            asm volatile("s_waitcnt vmcnt(24)" ::: "memory");
        } else {
            asm volatile("s_waitcnt vmcnt(0)" ::: "memory");
        }

        const int tcnt = (T - cs < TCH) ? (T - cs) : TCH;
        const float* L = &lds[nb][gl * 3];   // 12B/pair-step; 16 addrs, conflict-free
        #pragma unroll 8
        for (int tt = 0; tt < tcnt; ++tt) {
            const float P = L[0], Tt = L[1], E = L[2];
            L += ROWDW;
            const v2f q = step(P, Tt, E);
            *(v2f*)(ob + ooff) = q;          // dwordx2; 512B contiguous per wave
            ooff += ostep;
        }
    }
    #undef ISSUE_CHUNK
}

extern "C" void kernel_launch(void* const* d_in, const int* in_sizes, int n_in,
                              void* d_out, int out_size, void* d_ws, size_t ws_size,
                              hipStream_t stream) {
    const float* x    = (const float*)d_in[0];   // [T, G, 3]
    const float* praw = (const float*)d_in[1];   // [1, G, 12, 8]
    float* out = (float*)d_out;                  // [T, G, 8]

    const int G = in_sizes[1] / (NPAR * NM);     // 4000
    const int T = in_sizes[0] / (3 * G);         // 730

    const int grid = G / GPB;                    // 250 single-wave blocks
    hbv_kernel<<<grid, 64, 0, stream>>>(x, praw, out, G, T);
}

// Round 15
// 82.110 us; speedup vs baseline: 1.6594x; 1.6594x over previous
//
#include <hip/hip_runtime.h>
#include <math.h>
#include <stdint.h>

#define NM 8          // nmul
#define NPAR 12
#define KS 32         // timesteps per pipeline round (= forcing chunk)
#define NLL 3         // 1KB global_load_lds ops per forcing chunk (KS*96/1024)

typedef __attribute__((address_space(1))) const void gv_t;
typedef __attribute__((address_space(3))) void lv_t;

// Block = 128 threads = 2 waves, 64 chains (8 g x 8 m).
// Wave 0 (producer): forcing staging + snow routine (SP, MW) -> relays (rt, E).
// Wave 1 (consumer): soil + response (SM, SUZ, SLZ) -> stores Q. One round behind.
__global__ __launch_bounds__(128, 1) void hbv_kernel(
    const float* __restrict__ x,      // [T, G, 3]  (prcp, tmean, pet)
    const float* __restrict__ praw,   // [1, G, 12, NM] in [0,1)
    float* __restrict__ out,          // [T, G, NM]
    int G, int T)
{
    __shared__ float  fbuf[2][KS * 24];     // forcing chunks (producer only), 6 KB
    __shared__ float2 ring[2][KS][64];      // (rt, E) relay producer->consumer, 32 KB

    const int wid  = threadIdx.x >> 6;      // wave id: 0 producer, 1 consumer
    const int lane = threadIdx.x & 63;
    const int b    = blockIdx.x;
    const int g0   = b << 3;
    const int gl   = lane >> 3;             // g within block
    const int m    = lane & 7;
    const int g    = g0 + gl;

    // Parameter bounds: BETA, FC, K0, K1, K2, LP, PERC, UZL, TT, CFMAX, CFR, CWH
    const float lb[NPAR] = {1.0f, 50.0f, 0.05f, 0.01f, 0.001f, 0.2f, 0.0f, 0.0f, -2.5f, 0.5f, 0.0f, 0.0f};
    const float ub[NPAR] = {6.0f, 1000.0f, 0.9f, 0.5f, 0.2f, 1.0f, 10.0f, 100.0f, 2.5f, 10.0f, 0.1f, 0.2f};

    float p[NPAR];
    const float* pr = praw + (size_t)g * (NPAR * NM) + m;
    #pragma unroll
    for (int i = 0; i < NPAR; ++i) p[i] = pr[i * NM] * (ub[i] - lb[i]) + lb[i];

    const int NBLK = (T + KS - 1) / KS;     // 23 rounds of work

    if (wid == 0) {
        // ------------------------- PRODUCER (snow) -------------------------
        const float TT = p[8], CFMAX = p[9], CFR = p[10], CWH = p[11];
        const float nCFMAX_TT   = -(CFMAX * TT);
        const float nCFRCFMAX   = -(CFR * CFMAX);
        const float CFRCFMAX_TT = (CFR * CFMAX) * TT;

        float SP = 0.001f, MW = 0.001f;

        // forcing chunk-copy geometry (16B-aligned: 96 = 6*16, G*12 = 48000)
        const char* xb = (const char*)x;
        const uint32_t xstep  = (uint32_t)G * 12u;
        const uint32_t gbase  = (uint32_t)g0 * 12u;
        const uint32_t lin    = (uint32_t)lane * 16u;
        const uint32_t r0     = lin / 96u;
        const uint32_t c0     = lin % 96u;          // in {0,16,32,48,64,80}
        const uint32_t rowmax = (uint32_t)(T - 1);

        #define ISSUE_CHUNK(cs_, nb_)                                          \
        {                                                                      \
            uint32_t row_ = (uint32_t)(cs_) + r0;                              \
            uint32_t col_ = c0;                                                \
            _Pragma("unroll")                                                  \
            for (int i_ = 0; i_ < NLL; ++i_) {                                 \
                const uint32_t rg_ = row_ < rowmax ? row_ : rowmax;            \
                const uint32_t go_ = rg_ * xstep + gbase + col_;               \
                __builtin_amdgcn_global_load_lds((gv_t*)(xb + go_),            \
                    (lv_t*)&fbuf[nb_][i_ * 256], 16, 0, 0);                    \
                /* +1024B = 10 rows + 64B within the 96B-row raster */         \
                row_ += 10u + (col_ >= 32u ? 1u : 0u);                         \
                col_  = (col_ >= 32u) ? (col_ - 32u) : (col_ + 64u);           \
            }                                                                  \
        }

        ISSUE_CHUNK(0, 0)

        for (int r = 0; r <= NBLK; ++r) {
            if (r < NBLK) {
                if (r + 1 < NBLK) {
                    ISSUE_CHUNK((r + 1) * KS, (r + 1) & 1)
                    // newest 3 outstanding = next chunk; <=3 left means THIS
                    // chunk's copies have retired.
                    asm volatile("s_waitcnt vmcnt(3)" ::: "memory");
                } else {
                    asm volatile("s_waitcnt vmcnt(0)" ::: "memory");
                }
                const int cnt = (T - r * KS < KS) ? (T - r * KS) : KS;
                const float*  F = &fbuf[r & 1][gl * 3];
                float2*       R = &ring[r & 1][0][lane];
                #pragma unroll 4
                for (int tt = 0; tt < cnt; ++tt) {
                    const float P = F[0], Tt = F[1], E = F[2];
                    F += 24;
                    const float RAIN = (Tt >= TT) ? P : 0.0f;
                    const float SNOW = P - RAIN;
                    const float mc = fmaxf(fmaf(CFMAX, Tt, nCFMAX_TT), 0.0f);
                    const float rc = fmaxf(fmaf(nCFRCFMAX, Tt, CFRCFMAX_TT), 0.0f);
                    SP += SNOW;
                    const float melt = fminf(mc, SP);
                    MW += melt;
                    SP -= melt;
                    const float refr = fminf(rc, MW);
                    SP += refr;
                    MW -= refr;
                    const float cw = CWH * SP;
                    const float ts = fmaxf(MW - cw, 0.0f);
                    MW = fminf(MW, cw);                     // == MW - ts
                    float2 rel; rel.x = RAIN + ts; rel.y = E;
                    *R = rel;                               // ds_write_b64
                    R += 64;
                }
            }
            __syncthreads();
        }
        #undef ISSUE_CHUNK
    } else {
        // --------------------- CONSUMER (soil + response) ---------------------
        const float BETA = p[0], FC = p[1], K0 = p[2], K1 = p[3], K2 = p[4],
                    LP = p[5], PERCc = p[6], UZL = p[7];
        const float invLPFC = 1.0f / (LP * FC);
        const float nBLFC   = -BETA * __builtin_amdgcn_logf(FC);  // -BETA*log2(FC)
        const float OMK0    = 1.0f - K0;
        const float K0UZL   = K0 * UZL;
        const float OMK1    = 1.0f - K1;
        const float OMK2    = 1.0f - K2;

        float SM = 0.001f, SUZ = 0.001f, SLZ = 0.001f;

        char* ob = (char*)out;
        uint32_t ooff = (uint32_t)(g * NM + m) * 4u;
        const uint32_t ostep = (uint32_t)(G * NM) * 4u;

        for (int r = 0; r <= NBLK; ++r) {
            if (r >= 1) {
                const int base = (r - 1) * KS;
                const int cnt  = (T - base < KS) ? (T - base) : KS;
                const float2* R = &ring[(r - 1) & 1][0][lane];
                #pragma unroll 4
                for (int tt = 0; tt < cnt; ++tt) {
                    const float2 rel = *R;                  // ds_read_b64
                    R += 64;
                    const float rt = rel.x, E = rel.y;

                    // --- soil routine ---
                    const float lg = __builtin_amdgcn_logf(SM);
                    const float bl = fminf(fmaf(BETA, lg, nBLFC), 0.0f);
                    const float sw = __builtin_amdgcn_exp2f(bl);
                    const float rg = rt * sw;
                    const float SM1 = SM + rt - rg;
                    const float ex = fmaxf(SM1 - FC, 0.0f);
                    const float SM2 = fminf(SM1, FC);       // == SM1 - ex
                    const float omPe = fmaf(-E, invLPFC, 1.0f);   // 1 - PET/(LP*FC)
                    // SM2 - min3(SM2, SM2*Pe, E) == max3(SM2*(1-Pe), SM2-E, 0); eps subsumes 0
                    SM = fmaxf(fmaxf(SM2 * omPe, SM2 - E), 1e-5f);  // v_max3

                    // --- response routine (Q0+Q1 == s2 - s4) ---
                    SUZ = SUZ + rg + ex;
                    const float pc = fminf(SUZ, PERCc);
                    const float s2 = fmaxf(SUZ - PERCc, 0.0f);
                    const float s3 = fminf(s2, fmaf(OMK0, s2, K0UZL));
                    const float s4 = s3 * OMK1;
                    SUZ = s4;
                    const float sl = SLZ + pc;
                    const float q2 = K2 * sl;
                    SLZ = sl * OMK2;
                    const float Q = (s2 - s4) + q2;

                    *(float*)(ob + ooff) = Q;               // coalesced 256B/wave
                    ooff += ostep;
                }
            }
            __syncthreads();
        }
    }
}

extern "C" void kernel_launch(void* const* d_in, const int* in_sizes, int n_in,
                              void* d_out, int out_size, void* d_ws, size_t ws_size,
                              hipStream_t stream) {
    const float* x    = (const float*)d_in[0];   // [T, G, 3]
    const float* praw = (const float*)d_in[1];   // [1, G, 12, 8]
    float* out = (float*)d_out;                  // [T, G, 8]

    const int G = in_sizes[1] / (NPAR * NM);     // 4000
    const int T = in_sizes[0] / (3 * G);         // 730

    const int grid = G / 8;                      // 500 blocks x 2 waves = 1000 waves
    hbv_kernel<<<grid, 128, 0, stream>>>(x, praw, out, G, T);
}

// Round 16
// 70.871 us; speedup vs baseline: 1.9226x; 1.1586x over previous
//
#include <hip/hip_runtime.h>
#include <math.h>
#include <stdint.h>

#define NM 8          // nmul
#define NPAR 12
#define KS 32         // timesteps per pipeline round (= forcing chunk)
#define NLL 3         // 1KB global_load_lds ops per forcing chunk (KS*96/1024)

typedef __attribute__((address_space(1))) const void gv_t;
typedef __attribute__((address_space(3))) void lv_t;
typedef float v2f __attribute__((ext_vector_type(2)));

// Block = 128 threads = 2 waves, 64 chains (8 g x 8 m).
// Wave 0 (producer): staging + snow routine -> relays (rt, E) through LDS ring.
// Wave 1 (consumer): soil + response -> stores Q. One round behind.
// NEW vs R15: per-step LDS reads are issued 2 steps ahead via volatile asm,
// with a combined waitcnt+extract asm (data-dependence ordering, NO sched
// fences) so the ~120-cyc ds_read latency leaves the per-step serial path.
__global__ __launch_bounds__(128, 1) void hbv_kernel(
    const float* __restrict__ x,      // [T, G, 3]  (prcp, tmean, pet)
    const float* __restrict__ praw,   // [1, G, 12, NM] in [0,1)
    float* __restrict__ out,          // [T, G, NM]
    int G, int T)
{
    __shared__ float  fbuf[2][(KS + 2) * 24];   // +2 pad rows for t+2 prefetch
    __shared__ float2 ring[2][KS + 2][64];      // +2 pad rows

    const int wid  = threadIdx.x >> 6;      // 0 producer, 1 consumer
    const int lane = threadIdx.x & 63;
    const int b    = blockIdx.x;
    const int g0   = b << 3;
    const int gl   = lane >> 3;             // g within block
    const int m    = lane & 7;
    const int g    = g0 + gl;

    // Parameter bounds: BETA, FC, K0, K1, K2, LP, PERC, UZL, TT, CFMAX, CFR, CWH
    const float lb[NPAR] = {1.0f, 50.0f, 0.05f, 0.01f, 0.001f, 0.2f, 0.0f, 0.0f, -2.5f, 0.5f, 0.0f, 0.0f};
    const float ub[NPAR] = {6.0f, 1000.0f, 0.9f, 0.5f, 0.2f, 1.0f, 10.0f, 100.0f, 2.5f, 10.0f, 0.1f, 0.2f};

    float p[NPAR];
    const float* pr = praw + (size_t)g * (NPAR * NM) + m;
    #pragma unroll
    for (int i = 0; i < NPAR; ++i) p[i] = pr[i * NM] * (ub[i] - lb[i]) + lb[i];

    const int NBLK = (T + KS - 1) / KS;     // 23 rounds of work

    // issue one forcing-row read (P,T via read2; E single) -- 2 DS ops
    #define ISSUE_F(fa_, pt_, e_)                                              \
        asm volatile("ds_read2_b32 %0, %2 offset0:0 offset1:1\n\t"             \
                     "ds_read_b32 %1, %2 offset:8"                             \
                     : "=v"(pt_), "=v"(e_) : "v"(fa_));
    // wait until this slot's reads done (<=2 newer DS ops allowed in flight),
    // then extract; "+v"-style data deps order all consumers after the wait.
    #define WAIT_F(pt_, e_, P_, T_, E_)                                        \
        asm volatile("s_waitcnt lgkmcnt(2)\n\t"                                \
                     "v_mov_b32 %0, %3\n\t"                                    \
                     "v_mov_b32 %1, %4\n\t"                                    \
                     "v_mov_b32 %2, %5"                                        \
                     : "=v"(P_), "=v"(T_), "=v"(E_)                            \
                     : "v"(pt_.x), "v"(pt_.y), "v"(e_));
    // consumer ring read (1 DS op) + wait/extract (<=1 newer read in flight)
    #define ISSUE_C(ca_, rel_)                                                 \
        asm volatile("ds_read_b64 %0, %1" : "=v"(rel_) : "v"(ca_));
    #define WAIT_C(rel_, rt_, E_)                                              \
        asm volatile("s_waitcnt lgkmcnt(1)\n\t"                                \
                     "v_mov_b32 %0, %2\n\t"                                    \
                     "v_mov_b32 %1, %3"                                        \
                     : "=v"(rt_), "=v"(E_) : "v"(rel_.x), "v"(rel_.y));

    if (wid == 0) {
        // ------------------------- PRODUCER (snow) -------------------------
        const float TT = p[8], CFMAX = p[9], CFR = p[10], CWH = p[11];
        const float nCFMAX_TT   = -(CFMAX * TT);
        const float nCFRCFMAX   = -(CFR * CFMAX);
        const float CFRCFMAX_TT = (CFR * CFMAX) * TT;

        float SP = 0.001f, MW = 0.001f;

        // forcing chunk-copy geometry (16B-aligned: 96 = 6*16, G*12 = 48000)
        const char* xb = (const char*)x;
        const uint32_t xstep  = (uint32_t)G * 12u;
        const uint32_t gbase  = (uint32_t)g0 * 12u;
        const uint32_t lin    = (uint32_t)lane * 16u;
        const uint32_t r0     = lin / 96u;
        const uint32_t c0     = lin % 96u;          // in {0,16,32,48,64,80}
        const uint32_t rowmax = (uint32_t)(T - 1);

        #define ISSUE_CHUNK(cs_, nb_)                                          \
        {                                                                      \
            uint32_t row_ = (uint32_t)(cs_) + r0;                              \
            uint32_t col_ = c0;                                                \
            _Pragma("unroll")                                                  \
            for (int i_ = 0; i_ < NLL; ++i_) {                                 \
                const uint32_t rg_ = row_ < rowmax ? row_ : rowmax;            \
                const uint32_t go_ = rg_ * xstep + gbase + col_;               \
                __builtin_amdgcn_global_load_lds((gv_t*)(xb + go_),            \
                    (lv_t*)&fbuf[nb_][i_ * 256], 16, 0, 0);                    \
                /* +1024B = 10 rows + 64B within the 96B-row raster */         \
                row_ += 10u + (col_ >= 32u ? 1u : 0u);                         \
                col_  = (col_ >= 32u) ? (col_ - 32u) : (col_ + 64u);           \
            }                                                                  \
        }

        ISSUE_CHUNK(0, 0)

        for (int r = 0; r <= NBLK; ++r) {
            if (r < NBLK) {
                if (r + 1 < NBLK) {
                    ISSUE_CHUNK((r + 1) * KS, (r + 1) & 1)
                    asm volatile("s_waitcnt vmcnt(3)" ::: "memory");
                } else {
                    asm volatile("s_waitcnt vmcnt(0)" ::: "memory");
                }
                const int cnt = (T - r * KS < KS) ? (T - r * KS) : KS;  // 32 or 26: even
                uint32_t fa = (uint32_t)(uintptr_t)&fbuf[r & 1][gl * 3];
                float2*  R  = &ring[r & 1][0][lane];

                v2f pt0, pt1; float e0, e1;
                ISSUE_F(fa, pt0, e0) fa += 96;       // row 0
                ISSUE_F(fa, pt1, e1) fa += 96;       // row 1

                #define PROD_STEP(PT_, E_)                                     \
                {                                                              \
                    float P, Tt, E;                                            \
                    WAIT_F(PT_, E_, P, Tt, E)                                  \
                    ISSUE_F(fa, PT_, E_) fa += 96;   /* row tt+2 (pad safe) */ \
                    const float RAIN = (Tt >= TT) ? P : 0.0f;                  \
                    const float SNOW = P - RAIN;                               \
                    const float mc = fmaxf(fmaf(CFMAX, Tt, nCFMAX_TT), 0.0f);  \
                    const float rc = fmaxf(fmaf(nCFRCFMAX, Tt, CFRCFMAX_TT), 0.0f); \
                    SP += SNOW;                                                \
                    const float melt = fminf(mc, SP);                          \
                    MW += melt;                                                \
                    SP -= melt;                                                \
                    const float refr = fminf(rc, MW);                          \
                    SP += refr;                                                \
                    MW -= refr;                                                \
                    const float cw = CWH * SP;                                 \
                    const float ts = fmaxf(MW - cw, 0.0f);                     \
                    MW = fminf(MW, cw);                                        \
                    float2 rel; rel.x = RAIN + ts; rel.y = E;                  \
                    *R = rel;                                                  \
                    R += 64;                                                   \
                }

                for (int tt = 0; tt < cnt; tt += 2) {
                    PROD_STEP(pt0, e0)
                    PROD_STEP(pt1, e1)
                }
                #undef PROD_STEP
            }
            __syncthreads();
        }
        #undef ISSUE_CHUNK
    } else {
        // --------------------- CONSUMER (soil + response) ---------------------
        const float BETA = p[0], FC = p[1], K0 = p[2], K1 = p[3], K2 = p[4],
                    LP = p[5], PERCc = p[6], UZL = p[7];
        const float invLPFC = 1.0f / (LP * FC);
        const float nBLFC   = -BETA * __builtin_amdgcn_logf(FC);  // -BETA*log2(FC)
        const float OMK0    = 1.0f - K0;
        const float K0UZL   = K0 * UZL;
        const float OMK1    = 1.0f - K1;
        const float OMK2    = 1.0f - K2;

        float SM = 0.001f, SUZ = 0.001f, SLZ = 0.001f;

        char* ob = (char*)out;
        uint32_t ooff = (uint32_t)(g * NM + m) * 4u;
        const uint32_t ostep = (uint32_t)(G * NM) * 4u;

        for (int r = 0; r <= NBLK; ++r) {
            if (r >= 1) {
                const int base = (r - 1) * KS;
                const int cnt  = (T - base < KS) ? (T - base) : KS;   // even
                uint32_t ca = (uint32_t)(uintptr_t)&ring[(r - 1) & 1][0][lane];

                v2f rel0, rel1;
                ISSUE_C(ca, rel0) ca += 512;         // row 0 (512B = 64 float2)
                ISSUE_C(ca, rel1) ca += 512;         // row 1

                #define CONS_STEP(REL_)                                        \
                {                                                              \
                    float rt, E;                                               \
                    WAIT_C(REL_, rt, E)                                        \
                    ISSUE_C(ca, REL_) ca += 512;     /* row tt+2 (pad safe) */ \
                    const float lg = __builtin_amdgcn_logf(SM);                \
                    const float bl = fminf(fmaf(BETA, lg, nBLFC), 0.0f);       \
                    const float sw = __builtin_amdgcn_exp2f(bl);               \
                    const float rg = rt * sw;                                  \
                    const float SM1 = SM + rt - rg;                            \
                    const float ex = fmaxf(SM1 - FC, 0.0f);                    \
                    const float SM2 = fminf(SM1, FC);                          \
                    const float omPe = fmaf(-E, invLPFC, 1.0f);                \
                    SM = fmaxf(fmaxf(SM2 * omPe, SM2 - E), 1e-5f);  /* max3 */ \
                    SUZ = SUZ + rg + ex;                                       \
                    const float pc = fminf(SUZ, PERCc);                        \
                    const float s2 = fmaxf(SUZ - PERCc, 0.0f);                 \
                    const float s3 = fminf(s2, fmaf(OMK0, s2, K0UZL));         \
                    const float s4 = s3 * OMK1;                                \
                    SUZ = s4;                                                  \
                    const float sl = SLZ + pc;                                 \
                    const float q2 = K2 * sl;                                  \
                    SLZ = sl * OMK2;                                           \
                    const float Q = (s2 - s4) + q2;                            \
                    *(float*)(ob + ooff) = Q;                                  \
                    ooff += ostep;                                             \
                }

                for (int tt = 0; tt < cnt; tt += 2) {
                    CONS_STEP(rel0)
                    CONS_STEP(rel1)
                }
                #undef CONS_STEP
            }
            __syncthreads();
        }
    }
    #undef ISSUE_F
    #undef WAIT_F
    #undef ISSUE_C
    #undef WAIT_C
}

extern "C" void kernel_launch(void* const* d_in, const int* in_sizes, int n_in,
                              void* d_out, int out_size, void* d_ws, size_t ws_size,
                              hipStream_t stream) {
    const float* x    = (const float*)d_in[0];   // [T, G, 3]
    const float* praw = (const float*)d_in[1];   // [1, G, 12, 8]
    float* out = (float*)d_out;                  // [T, G, 8]

    const int G = in_sizes[1] / (NPAR * NM);     // 4000
    const int T = in_sizes[0] / (3 * G);         // 730

    const int grid = G / 8;                      // 500 blocks x 2 waves = 1000 waves
    hbv_kernel<<<grid, 128, 0, stream>>>(x, praw, out, G, T);
}